// Round 1
// baseline (1096.216 us; speedup 1.0000x reference)
//
#include <hip/hip_runtime.h>
#include <math.h>

#define BB  512
#define TT  256
#define EMBD 364
#define HS  64
#define ECH 28            // e-chunk (364 = 13*28)
#define NCH 13
#define NC  192           // 3*HS combined output cols: [k|q|v]

// Static LDS: wt[28][192] + xs[64][28] = 7168 floats = 28 KB. k_tmp[64][68] aliases it.
// Dynamic LDS: q[256][64] + v[256][64] fp32 = 128 KB. Total 156 KB < 160 KB.
__global__ __launch_bounds__(256, 1) void head_fused(
    const float* __restrict__ x,
    const float* __restrict__ Wk, const float* __restrict__ bk_,
    const float* __restrict__ Wq, const float* __restrict__ bq_,
    const float* __restrict__ Wv, const float* __restrict__ bv_,
    float* __restrict__ out)
{
    const int b   = blockIdx.x;
    const int tid = threadIdx.x;
    extern __shared__ float dyn[];
    float* q_lds = dyn;             // [TT][HS]
    float* v_lds = dyn + TT * HS;   // [TT][HS]
    __shared__ float stage[ECH * NC + 64 * ECH];
    float* wt    = stage;           // [ECH][NC]
    float* xs    = stage + ECH * NC;// [64][ECH]
    float* k_tmp = stage;           // [64][68] (aliases wt/xs, 17408 B < 28672 B)

    const float* xb = x + (size_t)b * TT * EMBD;
    const int tx = tid & 31;        // col lane: cols {tx + 32*j}, j=0..5
    const int ty = tid >> 5;        // row group: rows {m0 + ty*8 + i}, i=0..7

    float bias[6];
    bias[0] = bk_[tx];      bias[1] = bk_[tx + 32];
    bias[2] = bq_[tx];      bias[3] = bq_[tx + 32];
    bias[4] = bv_[tx];      bias[5] = bv_[tx + 32];

    float k_row[HS];

    // ---------------- Phase 1: fused QKV projection (LDS-tiled fp32 GEMM) ----------------
    for (int m_iter = 0; m_iter < 4; ++m_iter) {
        const int m0 = m_iter * 64;
        float acc[8][6];
        #pragma unroll
        for (int i = 0; i < 8; ++i)
            #pragma unroll
            for (int j = 0; j < 6; ++j) acc[i][j] = 0.f;

        for (int ek = 0; ek < NCH; ++ek) {
            const int e0 = ek * ECH;
            __syncthreads();   // staging buffer free (also protects k_tmp reads of prev m_iter)
            for (int i = tid; i < ECH * NC; i += 256) {
                int e = i / NC, c = i % NC;
                const float* Wp = (c < 64) ? Wk : (c < 128 ? Wq : Wv);
                wt[i] = Wp[(e0 + e) * HS + (c & 63)];
            }
            for (int i = tid; i < 64 * ECH; i += 256) {
                int r = i / ECH, e = i % ECH;
                xs[i] = xb[(size_t)(m0 + r) * EMBD + e0 + e];
            }
            __syncthreads();
            #pragma unroll 4
            for (int e = 0; e < ECH; ++e) {
                float wv[6];
                #pragma unroll
                for (int j = 0; j < 6; ++j) wv[j] = wt[e * NC + tx + 32 * j];
                #pragma unroll
                for (int i = 0; i < 8; ++i) {
                    float xv = xs[(ty * 8 + i) * ECH + e];
                    #pragma unroll
                    for (int j = 0; j < 6; ++j) acc[i][j] += xv * wv[j];
                }
            }
        }
        __syncthreads();  // all reads of wt/xs done before k_tmp overwrite
        #pragma unroll
        for (int i = 0; i < 8; ++i) {
            int r  = ty * 8 + i;
            int rg = m0 + r;
            k_tmp[r * 68 + tx]       = acc[i][0] + bias[0];
            k_tmp[r * 68 + tx + 32]  = acc[i][1] + bias[1];
            q_lds[rg * HS + tx]      = acc[i][2] + bias[2];
            q_lds[rg * HS + tx + 32] = acc[i][3] + bias[3];
            v_lds[rg * HS + tx]      = acc[i][4] + bias[4];
            v_lds[rg * HS + tx + 32] = acc[i][5] + bias[5];
        }
        __syncthreads();  // k_tmp visible
        if ((tid >> 6) == m_iter) {
            int r = tid - m0;
            #pragma unroll
            for (int h = 0; h < HS; ++h) k_row[h] = k_tmp[r * 68 + h];
        }
    }
    __syncthreads();

    // ---------------- Phase 2: causal attention, thread t = row ----------------
    const int t = tid;
    float m = -INFINITY, l = 0.f;
    float oacc[HS];
    #pragma unroll
    for (int h = 0; h < HS; ++h) oacc[h] = 0.f;

    const int s_hi = t | 63;   // wave-uniform causal bound
    for (int s = 0; s <= s_hi; ++s) {
        float w = 0.f;
        const float4* qs = (const float4*)(q_lds + s * HS);
        #pragma unroll
        for (int h4 = 0; h4 < 16; ++h4) {
            float4 qq = qs[h4];
            w += k_row[4 * h4 + 0] * qq.x;
            w += k_row[4 * h4 + 1] * qq.y;
            w += k_row[4 * h4 + 2] * qq.z;
            w += k_row[4 * h4 + 3] * qq.w;
        }
        w *= 0.125f;                      // HS^-0.5
        if (s > t) w = -INFINITY;         // causal mask
        if (w > m) {                      // online-softmax rescale (first iter: exp(-inf)=0)
            float f = __expf(m - w);
            l *= f;
            #pragma unroll
            for (int h = 0; h < HS; ++h) oacc[h] *= f;
            m = w;
        }
        float p = __expf(w - m);          // masked lanes: exp(-inf - m) = 0
        l += p;
        const float4* vs = (const float4*)(v_lds + s * HS);
        #pragma unroll
        for (int h4 = 0; h4 < 16; ++h4) {
            float4 vv = vs[h4];
            oacc[4 * h4 + 0] += p * vv.x;
            oacc[4 * h4 + 1] += p * vv.y;
            oacc[4 * h4 + 2] += p * vv.z;
            oacc[4 * h4 + 3] += p * vv.w;
        }
    }
    float inv = 1.0f / l;
    float* op = out + ((size_t)b * TT + t) * HS;
    #pragma unroll
    for (int h4 = 0; h4 < 16; ++h4) {
        float4 o;
        o.x = oacc[4 * h4 + 0] * inv;
        o.y = oacc[4 * h4 + 1] * inv;
        o.z = oacc[4 * h4 + 2] * inv;
        o.w = oacc[4 * h4 + 3] * inv;
        ((float4*)op)[h4] = o;
    }
}

extern "C" void kernel_launch(void* const* d_in, const int* in_sizes, int n_in,
                              void* d_out, int out_size, void* d_ws, size_t ws_size,
                              hipStream_t stream) {
    const float* x  = (const float*)d_in[0];
    const float* Wk = (const float*)d_in[1];
    const float* bk = (const float*)d_in[2];
    const float* Wq = (const float*)d_in[3];
    const float* bq = (const float*)d_in[4];
    const float* Wv = (const float*)d_in[5];
    const float* bv = (const float*)d_in[6];
    float* out = (float*)d_out;

    // >64 KB dynamic LDS: set opt-in attribute (idempotent, not a stream op — capture-safe).
    hipFuncSetAttribute((const void*)head_fused,
                        hipFuncAttributeMaxDynamicSharedMemorySize, 131072);
    head_fused<<<dim3(BB), dim3(256), 131072, stream>>>(x, Wk, bk, Wq, bq, Wv, bv, out);
}

// Round 2
// 249.085 us; speedup vs baseline: 4.4010x; 4.4010x over previous
//
#include <hip/hip_runtime.h>
#include <math.h>

#define BB   512
#define TT   256
#define EMBD 364
#define HS   64

typedef __attribute__((ext_vector_type(8))) short short8_t;  // 8 bf16 = 4 VGPRs
typedef __attribute__((ext_vector_type(4))) float f32x4;

__device__ __forceinline__ ushort f2bf(float v) {
    union { float f; unsigned u; } c; c.f = v;
    unsigned b = c.u;
    return (ushort)((b + 0x7FFF + ((b >> 16) & 1)) >> 16);   // RNE
}

// LDS carve (ushorts): kb[256][72] qb[256][72] vbT[64][264] xs[64][40] wsT[192][40] pb[8][16][40]
// = 18432+18432+16896+2560+7680+5120 ushorts = 138240 B  (< 160 KiB)
#define KB_OFF   0
#define QB_OFF   (TT*72)
#define VBT_OFF  (QB_OFF + TT*72)
#define XS_OFF   (VBT_OFF + 64*264)
#define WST_OFF  (XS_OFF + 64*40)
#define PB_OFF   (WST_OFF + 192*40)
#define LDS_BYTES ((PB_OFF + 8*16*40) * 2)

__global__ __launch_bounds__(512, 2) void head_mfma(
    const float* __restrict__ x,
    const float* __restrict__ Wk, const float* __restrict__ bk_,
    const float* __restrict__ Wq, const float* __restrict__ bq_,
    const float* __restrict__ Wv, const float* __restrict__ bv_,
    float* __restrict__ out)
{
    const int b   = blockIdx.x;
    const int tid = threadIdx.x;
    const int l   = tid & 63;
    const int w   = tid >> 6;          // wave 0..7
    const int l15 = l & 15;
    const int lg  = l >> 4;            // 0..3

    extern __shared__ ushort sm[];
    ushort* kb  = sm + KB_OFF;
    ushort* qb  = sm + QB_OFF;
    ushort* vbT = sm + VBT_OFF;
    ushort* xs  = sm + XS_OFF;
    ushort* wsT = sm + WST_OFF;
    ushort* pbw = sm + PB_OFF + w * (16 * 40);

    const float* xb = x + (size_t)b * TT * EMBD;

    const int nhalf = w & 1;           // phase-1 N half (6 n-tiles each)
    const int msub  = w >> 1;          // phase-1 M sub-tile (16 rows each)

    float bias6[6];
    #pragma unroll
    for (int j = 0; j < 6; ++j) {
        int c = (nhalf * 6 + j) * 16 + l15;
        bias6[j] = (c < 64) ? bk_[c] : (c < 128 ? bq_[c - 64] : bv_[c - 128]);
    }

    // ================= Phase 1: QKV projection via MFMA =================
    for (int mi = 0; mi < 4; ++mi) {
        const int m0 = mi * 64;
        f32x4 acc[6];
        #pragma unroll
        for (int j = 0; j < 6; ++j) acc[j] = (f32x4){0.f, 0.f, 0.f, 0.f};

        for (int ks = 0; ks < 12; ++ks) {
            const int e0 = ks * 32;
            __syncthreads();           // staging buffers free
            // --- stage x chunk [64 rows][32 k] -> bf16 xs[64][40] ---
            {
                const int r  = tid >> 3;
                const int c0 = (tid & 7) * 4;
                ushort4 pk;
                if (ks < 11) {
                    const float4 v = *(const float4*)&xb[(size_t)(m0 + r) * EMBD + e0 + c0];
                    pk.x = f2bf(v.x); pk.y = f2bf(v.y); pk.z = f2bf(v.z); pk.w = f2bf(v.w);
                } else {
                    float vv[4];
                    #pragma unroll
                    for (int u = 0; u < 4; ++u) {
                        int e = e0 + c0 + u;
                        vv[u] = (e < EMBD) ? xb[(size_t)(m0 + r) * EMBD + e] : 0.f;
                    }
                    pk.x = f2bf(vv[0]); pk.y = f2bf(vv[1]); pk.z = f2bf(vv[2]); pk.w = f2bf(vv[3]);
                }
                *(ushort4*)&xs[r * 40 + c0] = pk;
            }
            // --- stage W chunk transposed: wsT[c][k], c in [0,192) over k|q|v ---
            {
                const int kk  = tid >> 4;       // 0..31
                const int sub = tid & 15;       // 12 cols each
                const bool kval = (e0 + kk) < EMBD;
                #pragma unroll
                for (int u = 0; u < 12; ++u) {
                    int c = sub * 12 + u;
                    const float* Wp = (c < 64) ? Wk : (c < 128 ? Wq : Wv);
                    float vv = kval ? Wp[(size_t)(e0 + kk) * HS + (c & 63)] : 0.f;
                    wsT[c * 40 + kk] = f2bf(vv);
                }
            }
            __syncthreads();
            // --- MFMA: A = x rows (msub tile), B = W cols (6 n-tiles) ---
            short8_t afr = *(const short8_t*)&xs[(msub * 16 + l15) * 40 + lg * 8];
            #pragma unroll
            for (int j = 0; j < 6; ++j) {
                short8_t bfr = *(const short8_t*)&wsT[((nhalf * 6 + j) * 16 + l15) * 40 + lg * 8];
                acc[j] = __builtin_amdgcn_mfma_f32_16x16x32_bf16(afr, bfr, acc[j], 0, 0, 0);
            }
        }
        // --- epilogue: +bias, write bf16 k (pre-scaled)/q/vT into LDS ---
        #pragma unroll
        for (int j = 0; j < 6; ++j) {
            int c = (nhalf * 6 + j) * 16 + l15;
            #pragma unroll
            for (int r = 0; r < 4; ++r) {
                int t = m0 + msub * 16 + lg * 4 + r;   // D row = (lane>>4)*4 + reg
                float val = acc[j][r] + bias6[j];
                if (c < 64)       kb[t * 72 + c]            = f2bf(val * 0.125f);
                else if (c < 128) qb[t * 72 + (c - 64)]     = f2bf(val);
                else              vbT[(c - 128) * 264 + t]  = f2bf(val);
            }
        }
    }
    __syncthreads();

    // ================= Phase 2: causal flash attention via MFMA =================
    #pragma unroll
    for (int half = 0; half < 2; ++half) {
        const int rt = half ? (15 - w) : w;     // balanced causal work: 9 chunks/wave
        const int t0 = rt * 16;
        float mr[4], lr[4];
        f32x4 o[4];
        #pragma unroll
        for (int r = 0; r < 4; ++r) { mr[r] = -INFINITY; lr[r] = 0.f; }
        #pragma unroll
        for (int nt = 0; nt < 4; ++nt) o[nt] = (f32x4){0.f, 0.f, 0.f, 0.f};

        const int jd = t0 >> 5;
        for (int j = 0; j <= jd; ++j) {
            const int sb = j * 32;
            f32x4 sacc[2];
            sacc[0] = (f32x4){0.f, 0.f, 0.f, 0.f};
            sacc[1] = (f32x4){0.f, 0.f, 0.f, 0.f};
            #pragma unroll
            for (int kk = 0; kk < 2; ++kk) {
                short8_t afr = *(const short8_t*)&kb[(t0 + l15) * 72 + kk * 32 + lg * 8];
                #pragma unroll
                for (int ct = 0; ct < 2; ++ct) {
                    short8_t bfr = *(const short8_t*)&qb[(sb + ct * 16 + l15) * 72 + kk * 32 + lg * 8];
                    sacc[ct] = __builtin_amdgcn_mfma_f32_16x16x32_bf16(afr, bfr, sacc[ct], 0, 0, 0);
                }
            }
            // causal mask (scale already folded into kb)
            #pragma unroll
            for (int ct = 0; ct < 2; ++ct) {
                int s = sb + ct * 16 + l15;
                #pragma unroll
                for (int r = 0; r < 4; ++r) {
                    int t = t0 + lg * 4 + r;
                    if (s > t) sacc[ct][r] = -INFINITY;
                }
            }
            // online softmax: row = (lg*4+r), cols spread over l15 x 2 coltiles
            float p0[4], p1[4], fsc[4];
            #pragma unroll
            for (int r = 0; r < 4; ++r) {
                float mx = fmaxf(sacc[0][r], sacc[1][r]);
                mx = fmaxf(mx, __shfl_xor(mx, 1));
                mx = fmaxf(mx, __shfl_xor(mx, 2));
                mx = fmaxf(mx, __shfl_xor(mx, 4));
                mx = fmaxf(mx, __shfl_xor(mx, 8));
                float nm = fmaxf(mr[r], mx);
                fsc[r] = __expf(mr[r] - nm);
                mr[r] = nm;
                p0[r] = __expf(sacc[0][r] - nm);
                p1[r] = __expf(sacc[1][r] - nm);
                float ps = p0[r] + p1[r];
                ps += __shfl_xor(ps, 1);
                ps += __shfl_xor(ps, 2);
                ps += __shfl_xor(ps, 4);
                ps += __shfl_xor(ps, 8);
                lr[r] = lr[r] * fsc[r] + ps;
            }
            #pragma unroll
            for (int nt = 0; nt < 4; ++nt)
                #pragma unroll
                for (int r = 0; r < 4; ++r) o[nt][r] *= fsc[r];
            // P -> per-wave LDS tile (accum layout -> A-fragment layout)
            #pragma unroll
            for (int r = 0; r < 4; ++r) {
                pbw[(lg * 4 + r) * 40 + l15]      = f2bf(p0[r]);
                pbw[(lg * 4 + r) * 40 + 16 + l15] = f2bf(p1[r]);
            }
            short8_t pa = *(const short8_t*)&pbw[l15 * 40 + lg * 8];
            #pragma unroll
            for (int nt = 0; nt < 4; ++nt) {
                short8_t bfr = *(const short8_t*)&vbT[(nt * 16 + l15) * 264 + sb + lg * 8];
                o[nt] = __builtin_amdgcn_mfma_f32_16x16x32_bf16(pa, bfr, o[nt], 0, 0, 0);
            }
        }
        // epilogue: normalize, store fp32
        #pragma unroll
        for (int r = 0; r < 4; ++r) {
            float inv = 1.0f / lr[r];
            int t = t0 + lg * 4 + r;
            float* op = out + ((size_t)b * TT + t) * HS;
            #pragma unroll
            for (int nt = 0; nt < 4; ++nt)
                op[nt * 16 + l15] = o[nt][r] * inv;
        }
    }
}

extern "C" void kernel_launch(void* const* d_in, const int* in_sizes, int n_in,
                              void* d_out, int out_size, void* d_ws, size_t ws_size,
                              hipStream_t stream) {
    const float* x  = (const float*)d_in[0];
    const float* Wk = (const float*)d_in[1];
    const float* bk = (const float*)d_in[2];
    const float* Wq = (const float*)d_in[3];
    const float* bq = (const float*)d_in[4];
    const float* Wv = (const float*)d_in[5];
    const float* bv = (const float*)d_in[6];
    float* out = (float*)d_out;

    hipFuncSetAttribute((const void*)head_mfma,
                        hipFuncAttributeMaxDynamicSharedMemorySize, LDS_BYTES);
    head_mfma<<<dim3(BB), dim3(512), LDS_BYTES, stream>>>(x, Wk, bk, Wq, bq, Wv, bv, out);
}

// Round 3
// 114.767 us; speedup vs baseline: 9.5517x; 2.1704x over previous
//
#include <hip/hip_runtime.h>
#include <math.h>

#define BB   512
#define TT   256
#define EMBD 364
#define HS   64
#define KPAD 384
#define NC   192
#define LDX  136          // staging row pitch (ushorts): 272 B = 2*128+16 -> conflict-free b128

typedef __attribute__((ext_vector_type(8))) short short8_t;  // 8 bf16
typedef __attribute__((ext_vector_type(4))) float f32x4;

__device__ __forceinline__ ushort f2bf(float v) {
    union { float f; unsigned u; } c; c.f = v;
    unsigned b = c.u;
    return (ushort)((b + 0x7FFF + ((b >> 16) & 1)) >> 16);   // RNE
}

// ---------- kernel 0: W -> bf16 W^T [192][384] in d_ws, k-part pre-scaled by 0.125 ----------
__global__ void prep_wt(const float* __restrict__ Wk, const float* __restrict__ Wq,
                        const float* __restrict__ Wv, ushort* __restrict__ WT)
{
    const int c = blockIdx.x;                 // 0..191 output col of [k|q|v]
    const float* Wp = (c < 64) ? Wk : (c < 128 ? Wq : Wv);
    const float s  = (c < 64) ? 0.125f : 1.0f;
    const int col  = c & 63;
    for (int e = threadIdx.x; e < KPAD; e += 64) {
        float v = (e < EMBD) ? Wp[(size_t)e * HS + col] * s : 0.f;
        WT[(size_t)c * KPAD + e] = f2bf(v);
    }
}

// ---------- LDS carve (ushort offsets) ----------
// staging:  xsh[256][136] (34816) + wsh[192][136] (26112)  = 60928 ushorts = 121856 B
// outputs (ALIAS staging, written after last MFMA):
//   kb[256][72] qb[256][72] vbT[64][264] pb[8][16][40] = 58880 ushorts = 117760 B
#define XSH_OFF 0
#define WSH_OFF (TT * LDX)
#define KB_OFF  0
#define QB_OFF  (TT * 72)
#define VBT_OFF (QB_OFF + TT * 72)
#define PB_OFF  (VBT_OFF + 64 * 264)
#define LDS_USHORT (WSH_OFF + NC * LDX)
#define LDS_BYTES  (LDS_USHORT * 2)

__global__ __launch_bounds__(512, 2) void head_mfma(
    const float* __restrict__ x, const ushort* __restrict__ WT,
    const float* __restrict__ bk_, const float* __restrict__ bq_,
    const float* __restrict__ bv_, float* __restrict__ out)
{
    const int b   = blockIdx.x;
    const int tid = threadIdx.x;
    const int l   = tid & 63;
    const int w   = tid >> 6;          // wave 0..7
    const int l15 = l & 15;
    const int lg  = l >> 4;            // 0..3

    extern __shared__ ushort sm[];
    ushort* xsh = sm + XSH_OFF;
    ushort* wsh = sm + WSH_OFF;
    ushort* kb  = sm + KB_OFF;
    ushort* qb  = sm + QB_OFF;
    ushort* vbT = sm + VBT_OFF;
    ushort* pbw = sm + PB_OFF + w * (16 * 40);

    const float* xb = x + (size_t)b * TT * EMBD;

    const int nhalf = w & 1;           // N half: 6 col-tiles each
    const int msub  = w >> 1;          // 16-row sub-tile within each 64-row block

    float bias6[6];
    #pragma unroll
    for (int j = 0; j < 6; ++j) {
        int c = (nhalf * 6 + j) * 16 + l15;
        bias6[j] = (c < 64) ? bk_[c] * 0.125f : (c < 128 ? bq_[c - 64] : bv_[c - 128]);
    }

    // ================= Phase 1: QKV projection, full-M accumulators =================
    f32x4 acc[4][6];
    #pragma unroll
    for (int mi = 0; mi < 4; ++mi)
        #pragma unroll
        for (int j = 0; j < 6; ++j) acc[mi][j] = (f32x4){0.f, 0.f, 0.f, 0.f};

    for (int kc = 0; kc < 3; ++kc) {
        const int K0 = kc * 128;
        __syncthreads();               // staging buffers free
        // --- stage x[256][K0..K0+128) -> bf16 xsh ---
        #pragma unroll
        for (int it = 0; it < 8; ++it) {
            int r  = it * 32 + (tid >> 4);
            int c8 = (tid & 15) * 8;
            float v[8];
            if (kc < 2) {
                float4 a0 = *(const float4*)&xb[(size_t)r * EMBD + K0 + c8];
                float4 a1 = *(const float4*)&xb[(size_t)r * EMBD + K0 + c8 + 4];
                v[0] = a0.x; v[1] = a0.y; v[2] = a0.z; v[3] = a0.w;
                v[4] = a1.x; v[5] = a1.y; v[6] = a1.z; v[7] = a1.w;
            } else {
                #pragma unroll
                for (int u = 0; u < 8; ++u) {
                    int e = K0 + c8 + u;
                    v[u] = (e < EMBD) ? xb[(size_t)r * EMBD + e] : 0.f;
                }
            }
            union { short8_t s8; ushort us[8]; } pk;
            #pragma unroll
            for (int u = 0; u < 8; ++u) pk.us[u] = f2bf(v[u]);
            *(short8_t*)&xsh[r * LDX + c8] = pk.s8;
        }
        // --- stage W^T bf16 chunk [192][128] from d_ws ---
        if (tid < 384) {
            int rc = tid >> 1, ch = tid & 1;
            #pragma unroll
            for (int u = 0; u < 8; ++u) {
                short8_t wv = *(const short8_t*)&WT[(size_t)rc * KPAD + K0 + ch * 64 + u * 8];
                *(short8_t*)&wsh[rc * LDX + ch * 64 + u * 8] = wv;
            }
        }
        __syncthreads();
        // --- MFMAs: 4 ks * 6 j * 4 mi = 96 per wave per chunk ---
        #pragma unroll
        for (int ks = 0; ks < 4; ++ks) {
            short8_t a[4];
            #pragma unroll
            for (int mi = 0; mi < 4; ++mi)
                a[mi] = *(const short8_t*)&xsh[(mi * 64 + msub * 16 + l15) * LDX + ks * 32 + lg * 8];
            #pragma unroll
            for (int j = 0; j < 6; ++j) {
                short8_t bf = *(const short8_t*)&wsh[((nhalf * 6 + j) * 16 + l15) * LDX + ks * 32 + lg * 8];
                #pragma unroll
                for (int mi = 0; mi < 4; ++mi)
                    acc[mi][j] = __builtin_amdgcn_mfma_f32_16x16x32_bf16(a[mi], bf, acc[mi][j], 0, 0, 0);
            }
        }
    }
    __syncthreads();   // all staging reads done -> safe to overwrite with kqv

    // --- epilogue: +bias, write bf16 kb (pre-scaled via WT/bias) / qb / vbT ---
    #pragma unroll
    for (int mi = 0; mi < 4; ++mi)
        #pragma unroll
        for (int j = 0; j < 6; ++j) {
            int c = (nhalf * 6 + j) * 16 + l15;
            #pragma unroll
            for (int r = 0; r < 4; ++r) {
                int t = mi * 64 + msub * 16 + lg * 4 + r;
                float val = acc[mi][j][r] + bias6[j];
                if (c < 64)       kb[t * 72 + c]           = f2bf(val);
                else if (c < 128) qb[t * 72 + (c - 64)]    = f2bf(val);
                else              vbT[(c - 128) * 264 + t] = f2bf(val);
            }
        }
    __syncthreads();

    // ================= Phase 2: causal flash attention via MFMA =================
    #pragma unroll
    for (int half = 0; half < 2; ++half) {
        const int rt = half ? (15 - w) : w;     // balanced causal work: 9 chunks/wave
        const int t0 = rt * 16;
        float mr[4], lr[4];
        f32x4 o[4];
        #pragma unroll
        for (int r = 0; r < 4; ++r) { mr[r] = -INFINITY; lr[r] = 0.f; }
        #pragma unroll
        for (int nt = 0; nt < 4; ++nt) o[nt] = (f32x4){0.f, 0.f, 0.f, 0.f};

        const int jd = t0 >> 5;
        for (int j = 0; j <= jd; ++j) {
            const int sb = j * 32;
            f32x4 sacc[2];
            sacc[0] = (f32x4){0.f, 0.f, 0.f, 0.f};
            sacc[1] = (f32x4){0.f, 0.f, 0.f, 0.f};
            #pragma unroll
            for (int kk = 0; kk < 2; ++kk) {
                short8_t afr = *(const short8_t*)&kb[(t0 + l15) * 72 + kk * 32 + lg * 8];
                #pragma unroll
                for (int ct = 0; ct < 2; ++ct) {
                    short8_t bfr = *(const short8_t*)&qb[(sb + ct * 16 + l15) * 72 + kk * 32 + lg * 8];
                    sacc[ct] = __builtin_amdgcn_mfma_f32_16x16x32_bf16(afr, bfr, sacc[ct], 0, 0, 0);
                }
            }
            #pragma unroll
            for (int ct = 0; ct < 2; ++ct) {
                int s = sb + ct * 16 + l15;
                #pragma unroll
                for (int r = 0; r < 4; ++r) {
                    int t = t0 + lg * 4 + r;
                    if (s > t) sacc[ct][r] = -INFINITY;
                }
            }
            float p0[4], p1[4], fsc[4];
            #pragma unroll
            for (int r = 0; r < 4; ++r) {
                float mx = fmaxf(sacc[0][r], sacc[1][r]);
                mx = fmaxf(mx, __shfl_xor(mx, 1));
                mx = fmaxf(mx, __shfl_xor(mx, 2));
                mx = fmaxf(mx, __shfl_xor(mx, 4));
                mx = fmaxf(mx, __shfl_xor(mx, 8));
                float nm = fmaxf(mr[r], mx);
                fsc[r] = __expf(mr[r] - nm);
                mr[r] = nm;
                p0[r] = __expf(sacc[0][r] - nm);
                p1[r] = __expf(sacc[1][r] - nm);
                float ps = p0[r] + p1[r];
                ps += __shfl_xor(ps, 1);
                ps += __shfl_xor(ps, 2);
                ps += __shfl_xor(ps, 4);
                ps += __shfl_xor(ps, 8);
                lr[r] = lr[r] * fsc[r] + ps;
            }
            #pragma unroll
            for (int nt = 0; nt < 4; ++nt)
                #pragma unroll
                for (int r = 0; r < 4; ++r) o[nt][r] *= fsc[r];
            #pragma unroll
            for (int r = 0; r < 4; ++r) {
                pbw[(lg * 4 + r) * 40 + l15]      = f2bf(p0[r]);
                pbw[(lg * 4 + r) * 40 + 16 + l15] = f2bf(p1[r]);
            }
            short8_t pa = *(const short8_t*)&pbw[l15 * 40 + lg * 8];
            #pragma unroll
            for (int nt = 0; nt < 4; ++nt) {
                short8_t bfr = *(const short8_t*)&vbT[(nt * 16 + l15) * 264 + sb + lg * 8];
                o[nt] = __builtin_amdgcn_mfma_f32_16x16x32_bf16(pa, bfr, o[nt], 0, 0, 0);
            }
        }
        #pragma unroll
        for (int r = 0; r < 4; ++r) {
            float inv = 1.0f / lr[r];
            int t = t0 + lg * 4 + r;
            float* op = out + ((size_t)b * TT + t) * HS;
            #pragma unroll
            for (int nt = 0; nt < 4; ++nt)
                op[nt * 16 + l15] = o[nt][r] * inv;
        }
    }
}

extern "C" void kernel_launch(void* const* d_in, const int* in_sizes, int n_in,
                              void* d_out, int out_size, void* d_ws, size_t ws_size,
                              hipStream_t stream) {
    const float* x  = (const float*)d_in[0];
    const float* Wk = (const float*)d_in[1];
    const float* bk = (const float*)d_in[2];
    const float* Wq = (const float*)d_in[3];
    const float* bq = (const float*)d_in[4];
    const float* Wv = (const float*)d_in[5];
    const float* bv = (const float*)d_in[6];
    float* out = (float*)d_out;
    ushort* WT = (ushort*)d_ws;        // 192*384*2 = 147456 B

    prep_wt<<<dim3(NC), dim3(64), 0, stream>>>(Wk, Wq, Wv, WT);

    hipFuncSetAttribute((const void*)head_mfma,
                        hipFuncAttributeMaxDynamicSharedMemorySize, LDS_BYTES);
    head_mfma<<<dim3(BB), dim3(512), LDS_BYTES, stream>>>(x, WT, bk, bq, bv, out);
}